// Round 9
// baseline (193.400 us; speedup 1.0000x reference)
//
#include <hip/hip_runtime.h>
#include <hip/hip_bf16.h>
#include <math.h>

#define N_NODES 50000
#define N_EDGES 800000
#define HDIM 64

#define NBUCKET 392       // buckets of 128 nodes: 392*128 = 50176 >= 50000
#define BSHIFT  7
#define NLOC    128       // nodes per bucket
#define BCAP    3072      // mean 2048, sd ~45 -> ~22 sigma headroom
#define NVIRT   (NBUCKET * NLOC)   // 50176 virtual node slots

typedef short bf16x8 __attribute__((ext_vector_type(8)));
typedef float f32x4  __attribute__((ext_vector_type(4)));
typedef unsigned short ushort_t;

__device__ __forceinline__ ushort_t f2bf(float f) {
    __hip_bfloat16 b = __float2bfloat16(f);
    return *(ushort_t*)&b;
}

// ---------------------------------------------------------------------------
// Prep: [0,3125) features->bf16; [3125,3221) W transpose+convert;
// block 3221: zero bucketFill + scalar + done counter.
// ---------------------------------------------------------------------------
__global__ __launch_bounds__(256) void prep_kernel(
    const float* __restrict__ features, ushort_t* __restrict__ x_bf,
    const float* __restrict__ V, const float* __restrict__ lw,
    ushort_t* __restrict__ Wt, int* __restrict__ bucketFill,
    float* __restrict__ scalar, int* __restrict__ done)
{
    const int b = blockIdx.x;
    const int t = threadIdx.x;
    if (b < 3125) {
        const int i = b * 256 + t;                   // < 800000 float4s
        const float4 v = ((const float4*)features)[i];
        ushort4 o = { f2bf(v.x), f2bf(v.y), f2bf(v.z), f2bf(v.w) };
        *(ushort4*)&x_bf[(size_t)i * 4] = o;
    } else if (b < 3221) {
        const int e = (b - 3125) * 256 + t;          // < 24576
        const int l = e / 12288, r = e % 12288;
        const int n = r / 192, k = r % 192;
        const int sel = k >> 6, i = k & 63;
        const float val = (sel < 2) ? V[l * 8192 + sel * 4096 + i * 64 + n]
                                    : lw[l * 4096 + i * 64 + n];
        Wt[e] = f2bf(val);
    } else {
        for (int i = t; i < NBUCKET; i += 256) bucketFill[i] = 0;
        if (t == 0) { scalar[0] = 0.0f; done[0] = 0; }
    }
}

// ---------------------------------------------------------------------------
// K1: bucket scatter (R4 verbatim).
// ---------------------------------------------------------------------------
__global__ __launch_bounds__(256) void bucket_scatter(
    const int* __restrict__ src, const int* __restrict__ dst,
    const int* __restrict__ etype, int* __restrict__ bucketFill,
    unsigned int* __restrict__ buf)
{
    __shared__ int cnt[NBUCKET];
    __shared__ int base[NBUCKET];
    const int t = threadIdx.x;
    for (int i = t; i < NBUCKET; i += 256) cnt[i] = 0;
    __syncthreads();

    int rank[8], bkt[8];
    unsigned pay[8];
    bool valid[8];
#pragma unroll
    for (int k = 0; k < 8; ++k) {
        const int e = blockIdx.x * 2048 + k * 256 + t;
        valid[k] = (e < N_EDGES);
        if (valid[k]) {
            const int d = dst[e];
            const int b = d >> BSHIFT;
            bkt[k] = b;
            pay[k] = (unsigned)src[e] | ((unsigned)etype[e] << 16)
                   | ((unsigned)(d & (NLOC - 1)) << 19);
            rank[k] = atomicAdd(&cnt[b], 1);
        }
    }
    __syncthreads();
    for (int i = t; i < NBUCKET; i += 256)
        base[i] = atomicAdd(&bucketFill[i], cnt[i]);
    __syncthreads();
#pragma unroll
    for (int k = 0; k < 8; ++k) {
        if (valid[k]) {
            const int pos = base[bkt[k]] + rank[k];
            if (pos < BCAP) buf[bkt[k] * BCAP + pos] = pay[k];
        }
    }
}

// ---------------------------------------------------------------------------
// K2: per-bucket sort + degree-sorted node permutation.
// One block per bucket (392): hist over 128 local nodes, wave-scan, row_ptr,
// final edge placement, PLUS counting-sort of the 128 local nodes by degree
// into perm[] so aggregate waves draw similar-degree nodes (max ~= mean).
// ---------------------------------------------------------------------------
__global__ __launch_bounds__(256) void bucket_sort(
    const unsigned int* __restrict__ buf, const int* __restrict__ bucketFill,
    unsigned int* __restrict__ edges, int* __restrict__ row_ptr,
    int* __restrict__ perm)
{
    __shared__ int hist[NLOC];
    __shared__ int lscan[NLOC];
    __shared__ int cnt2[NLOC];
    __shared__ int sraw[448];
    __shared__ int sexc[448];
    __shared__ int dh[64];
    const int b = blockIdx.x;
    const int t = threadIdx.x;

    if (t < NLOC) { hist[t] = 0; cnt2[t] = 0; }
    for (int i = t; i < 448; i += 256)
        sraw[i] = (i < NBUCKET) ? bucketFill[i] : 0;
    __syncthreads();

    // exclusive prefix over 392 bucket totals: wave 0, 7 chunks of 64
    if (t < 64) {
        int carry = 0;
        for (int c = 0; c < 7; ++c) {
            const int h = sraw[c * 64 + t];
            int x = h;
#pragma unroll
            for (int off = 1; off < 64; off <<= 1) {
                int u = __shfl_up(x, off, 64);
                if (t >= off) x += u;
            }
            sexc[c * 64 + t] = carry + x - h;
            carry += __shfl(x, 63, 64);
        }
    }
    __syncthreads();
    const int cntb = min(sraw[b], BCAP);
    const int bb   = sexc[b];

    // pass 1: node histogram, 4 loads in flight
    for (int i0 = t; i0 < cntb; i0 += 1024) {
        const bool v1 = i0 + 256 < cntb, v2 = i0 + 512 < cntb, v3 = i0 + 768 < cntb;
        const unsigned p0 = buf[b * BCAP + i0];
        unsigned p1 = 0, p2 = 0, p3 = 0;
        if (v1) p1 = buf[b * BCAP + i0 + 256];
        if (v2) p2 = buf[b * BCAP + i0 + 512];
        if (v3) p3 = buf[b * BCAP + i0 + 768];
        atomicAdd(&hist[p0 >> 19], 1);
        if (v1) atomicAdd(&hist[p1 >> 19], 1);
        if (v2) atomicAdd(&hist[p2 >> 19], 1);
        if (v3) atomicAdd(&hist[p3 >> 19], 1);
    }
    __syncthreads();

    // exclusive scan of 128 node counts: wave 0, 2 chunks of 64
    if (t < 64) {
        int carry = 0;
        for (int c = 0; c < 2; ++c) {
            const int h = hist[c * 64 + t];
            int x = h;
#pragma unroll
            for (int off = 1; off < 64; off <<= 1) {
                int u = __shfl_up(x, off, 64);
                if (t >= off) x += u;
            }
            lscan[c * 64 + t] = carry + x - h;
            carry += __shfl(x, 63, 64);
        }
    }
    __syncthreads();

    // row_ptr (coalesced)
    const int n0 = b << BSHIFT;
    if (t < NLOC) {
        const int g = n0 + t;
        if (g < N_NODES) row_ptr[g] = bb + lscan[t];
    }
    if (b == NBUCKET - 1 && t == 0) row_ptr[N_NODES] = bb + cntb;

    // ---- degree-sorted permutation (counting sort over 64 degree bins) ----
    if (t < 64) dh[t] = 0;
    __syncthreads();
    if (t < NLOC) atomicAdd(&dh[min(hist[t], 63)], 1);
    __syncthreads();
    if (t < 64) {
        const int h = dh[t];
        int x = h;
#pragma unroll
        for (int off = 1; off < 64; off <<= 1) {
            int u = __shfl_up(x, off, 64);
            if (t >= off) x += u;
        }
        dh[t] = x - h;                    // exclusive offsets (reused as cursors)
    }
    __syncthreads();
    if (t < NLOC) {
        const int dr  = min(hist[t], 63);
        const int pos = atomicAdd(&dh[dr], 1);
        perm[n0 + pos] = n0 + t;
    }

    // pass 2: final placement, 4 loads in flight
    for (int i0 = t; i0 < cntb; i0 += 1024) {
        const bool v1 = i0 + 256 < cntb, v2 = i0 + 512 < cntb, v3 = i0 + 768 < cntb;
        const unsigned p0 = buf[b * BCAP + i0];
        unsigned p1 = 0, p2 = 0, p3 = 0;
        if (v1) p1 = buf[b * BCAP + i0 + 256];
        if (v2) p2 = buf[b * BCAP + i0 + 512];
        if (v3) p3 = buf[b * BCAP + i0 + 768];
        {
            const int d = p0 >> 19;
            const int r = atomicAdd(&cnt2[d], 1);
            edges[bb + lscan[d] + r] = p0;
        }
        if (v1) { const int d = p1 >> 19; const int r = atomicAdd(&cnt2[d], 1);
                  edges[bb + lscan[d] + r] = p1; }
        if (v2) { const int d = p2 >> 19; const int r = atomicAdd(&cnt2[d], 1);
                  edges[bb + lscan[d] + r] = p2; }
        if (v3) { const int d = p3 >> 19; const int r = atomicAdd(&cnt2[d], 1);
                  edges[bb + lscan[d] + r] = p3; }
    }
}

// ---------------------------------------------------------------------------
// Aggregate v7: v4 structure (16-lane group per node, 4 nodes/wave, 4 edges
// in flight) + degree-sorted virtual indexing: n = perm[vi], so the 4 nodes
// of a wave have similar degree and the lock-step loop wastes ~nothing.
// Grid covers all 50176 virtual slots; invalid nodes exit immediately.
// ---------------------------------------------------------------------------
__global__ __launch_bounds__(256) void aggregate_v7(
    const ushort_t* __restrict__ x,      // [N,64] bf16
    const unsigned int* __restrict__ edges,
    const int* __restrict__ row_ptr,
    const int* __restrict__ perm,        // [NVIRT]
    const float* __restrict__ comp_l,    // [8,2] f32
    ushort_t* __restrict__ y)            // [N,128] bf16
{
    __shared__ float scomp[16];
    const int t = threadIdx.x;
    if (t < 16) scomp[t] = comp_l[t];
    __syncthreads();

    const int lane = t & 63;
    const int wv   = t >> 6;
    const int g    = lane >> 4;          // node slot within wave (0..3)
    const int fq   = lane & 15;          // feature quad
    const int vi   = blockIdx.x * 16 + wv * 4 + g;   // < 50176
    const int n    = perm[vi];

    int beg = 0, end = 0;
    if (n < N_NODES) { beg = row_ptr[n]; end = row_ptr[n + 1]; }

    float a0[4], a1[4];
#pragma unroll
    for (int i = 0; i < 4; ++i) { a0[i] = 0.f; a1[i] = 0.f; }

    for (int j = beg; j < end; j += 4) {
        unsigned p[4];
#pragma unroll
        for (int k = 0; k < 4; ++k) {
            const int e = j + k;
            p[k] = edges[(e < end) ? e : (end - 1)];
        }
        uint2 u[4];
#pragma unroll
        for (int k = 0; k < 4; ++k)
            u[k] = *(const uint2*)&x[(size_t)(p[k] & 0xFFFFu) * 64 + fq * 4];
        float2 c[4];
#pragma unroll
        for (int k = 0; k < 4; ++k) {
            c[k] = *(const float2*)&scomp[((p[k] >> 16) & 7u) * 2];
            if (j + k >= end) { c[k].x = 0.f; c[k].y = 0.f; }
        }
#pragma unroll
        for (int k = 0; k < 4; ++k) {
            const float f0 = __uint_as_float(u[k].x << 16);
            const float f1 = __uint_as_float(u[k].x & 0xFFFF0000u);
            const float f2 = __uint_as_float(u[k].y << 16);
            const float f3 = __uint_as_float(u[k].y & 0xFFFF0000u);
            a0[0] = fmaf(c[k].x, f0, a0[0]); a1[0] = fmaf(c[k].y, f0, a1[0]);
            a0[1] = fmaf(c[k].x, f1, a0[1]); a1[1] = fmaf(c[k].y, f1, a1[1]);
            a0[2] = fmaf(c[k].x, f2, a0[2]); a1[2] = fmaf(c[k].y, f2, a1[2]);
            a0[3] = fmaf(c[k].x, f3, a0[3]); a1[3] = fmaf(c[k].y, f3, a1[3]);
        }
    }

    if (n < N_NODES) {
        ushort4 s0 = { f2bf(a0[0]), f2bf(a0[1]), f2bf(a0[2]), f2bf(a0[3]) };
        ushort4 s1 = { f2bf(a1[0]), f2bf(a1[1]), f2bf(a1[2]), f2bf(a1[3]) };
        *(ushort4*)&y[(size_t)n * 128 + fq * 4]      = s0;
        *(ushort4*)&y[(size_t)n * 128 + 64 + fq * 4] = s1;
    }
}

// ---------------------------------------------------------------------------
// MFMA node transform (R4 verbatim): h[0:64] = U[64x192] @ W[192x64] + bias.
//  !FUSE: writes relu(h) bf16.  FUSE: accumulates h . fc_w into scalar;
//  the last block to finish applies sigmoid and writes the output.
// ---------------------------------------------------------------------------
template <bool FUSE>
__global__ __launch_bounds__(256) void mfma_transform(
    const ushort_t* __restrict__ y_bf,   // [N,128]
    const ushort_t* __restrict__ x_bf,   // [N,64]
    const ushort_t* __restrict__ Wt,     // [64,192] this layer (n-major)
    const float* __restrict__ bias,      // [64] f32
    const float* __restrict__ fcw,       // [N*64] (FUSE)
    ushort_t* __restrict__ xout,         // [N,64] (!FUSE)
    float* __restrict__ scalar,          // [1]    (FUSE)
    const float* __restrict__ fcb,       // [1]    (FUSE)
    int* __restrict__ done,              // [1]    (FUSE)
    float* __restrict__ outp)            // [1]    (FUSE)
{
    __shared__ __align__(16) ushort_t su[64 * 200];   // 200 = 192 + 8 pad
    __shared__ float sred[4];
    const int t = threadIdx.x;
    const int w = t >> 6;
    const int lane = t & 63;
    const int c16 = lane & 15;
    const int quad = lane >> 4;
    const int tile = blockIdx.x;

    bf16x8 wf[6];
#pragma unroll
    for (int kf = 0; kf < 6; ++kf)
        wf[kf] = *(const bf16x8*)&Wt[(w * 16 + c16) * 192 + kf * 32 + quad * 8];
    const float bv = bias[w * 16 + c16];

#pragma unroll
    for (int k = 0; k < 6; ++k) {
        const int cid = t + 256 * k;          // 0..1535
        const int row = cid / 24;
        const int part = cid % 24;
        const int n = tile * 64 + row;
        uint4 v = {0u, 0u, 0u, 0u};
        if (n < N_NODES) {
            v = (part < 16) ? *(const uint4*)&y_bf[(size_t)n * 128 + part * 8]
                            : *(const uint4*)&x_bf[(size_t)n * 64 + (part - 16) * 8];
        }
        *(uint4*)&su[row * 200 + part * 8] = v;
    }
    __syncthreads();

    float fsum = 0.f;
#pragma unroll
    for (int mt = 0; mt < 4; ++mt) {
        f32x4 acc = {bv, bv, bv, bv};
#pragma unroll
        for (int kf = 0; kf < 6; ++kf) {
            const bf16x8 af =
                *(const bf16x8*)&su[(mt * 16 + c16) * 200 + kf * 32 + quad * 8];
            acc = __builtin_amdgcn_mfma_f32_16x16x32_bf16(af, wf[kf], acc, 0, 0, 0);
        }
        const int nodeb = tile * 64 + mt * 16 + quad * 4;
        if (FUSE) {
#pragma unroll
            for (int r = 0; r < 4; ++r) {
                const int n = nodeb + r;
                if (n < N_NODES)
                    fsum += acc[r] * fcw[(size_t)n * 64 + w * 16 + c16];
            }
        } else {
#pragma unroll
            for (int r = 0; r < 4; ++r) {
                const int n = nodeb + r;
                if (n < N_NODES)
                    xout[(size_t)n * 64 + w * 16 + c16] = f2bf(fmaxf(acc[r], 0.f));
            }
        }
    }

    if (FUSE) {
#pragma unroll
        for (int off = 32; off; off >>= 1) fsum += __shfl_down(fsum, off, 64);
        if (lane == 0) sred[w] = fsum;
        __syncthreads();
        if (t == 0) {
            atomicAdd(scalar, sred[0] + sred[1] + sred[2] + sred[3]);
            __threadfence();
            const int ticket = atomicAdd(done, 1);
            if (ticket == (int)gridDim.x - 1) {
                const float v = atomicAdd(scalar, 0.0f) + fcb[0];
                outp[0] = 1.0f / (1.0f + expf(-v));
            }
        }
    }
}

// ---------------------------------------------------------------------------
extern "C" void kernel_launch(void* const* d_in, const int* in_sizes, int n_in,
                              void* d_out, int out_size, void* d_ws, size_t ws_size,
                              hipStream_t stream)
{
    const float* features = (const float*)d_in[0];  // [50000, 64]
    const float* V        = (const float*)d_in[1];  // [2, 2, 64, 64]
    const float* comp     = (const float*)d_in[2];  // [2, 8, 2]
    const float* loop_w   = (const float*)d_in[3];  // [2, 64, 64]
    const float* bias     = (const float*)d_in[4];  // [2, 64]
    const float* fc_w     = (const float*)d_in[5];  // [1, 50000*64]
    const float* fc_b     = (const float*)d_in[6];  // [1]
    const int*   src      = (const int*)d_in[7];
    const int*   dst      = (const int*)d_in[8];
    const int*   etype    = (const int*)d_in[9];
    float* out = (float*)d_out;

    char* ws = (char*)d_ws;
    ushort_t*     y_bf    = (ushort_t*)(ws);                 // 12,800,000 B
    ushort_t*     x_bf    = (ushort_t*)(ws + 12800000);      //  6,400,000 B
    ushort_t*     x1_bf   = (ushort_t*)(ws + 19200000);      //  6,400,000 B
    ushort_t*     Wt      = (ushort_t*)(ws + 25600000);      //     49,152 B
    float*        scalar  = (float*)   (ws + 25649152);      //          4 B
    int*          done    = (int*)     (ws + 25649156);      //          4 B
    int*          bucketFill = (int*)  (ws + 25649280);      //      1,568 B
    int*          row_ptr = (int*)     (ws + 25650944);      //    200,004 B
    unsigned int* edges   = (unsigned int*)(ws + 25851008);  //  3,200,000 B
    unsigned int* buf     = (unsigned int*)(ws + 29051008);  //  4,816,896 B
    int*          perm    = (int*)     (ws + 33867904);      //    200,704 B
                                                             // end ~34.1 MB

    const int aggBlocks = NVIRT / 16;               // 3136 (covers 50176 slots)
    const int mtBlocks  = (N_NODES + 63) / 64;      // 782
    const int k1Blocks  = (N_EDGES + 2047) / 2048;  // 391

    // ---- prep (bf16 converts + zero counters) + bucketed CSR build ----
    prep_kernel<<<3222, 256, 0, stream>>>(features, x_bf, V, loop_w, Wt,
                                          bucketFill, scalar, done);
    bucket_scatter<<<k1Blocks, 256, 0, stream>>>(src, dst, etype, bucketFill, buf);
    bucket_sort<<<NBUCKET, 256, 0, stream>>>(buf, bucketFill, edges, row_ptr, perm);

    // ---- layer 0 ----
    aggregate_v7<<<aggBlocks, 256, 0, stream>>>(x_bf, edges, row_ptr, perm,
                                                comp, y_bf);
    mfma_transform<false><<<mtBlocks, 256, 0, stream>>>(
        y_bf, x_bf, Wt, bias, nullptr, x1_bf, nullptr, nullptr, nullptr, nullptr);

    // ---- layer 1 + fused FC dot + last-block sigmoid ----
    aggregate_v7<<<aggBlocks, 256, 0, stream>>>(x1_bf, edges, row_ptr, perm,
                                                comp + 16, y_bf);
    mfma_transform<true><<<mtBlocks, 256, 0, stream>>>(
        y_bf, x1_bf, Wt + 12288, bias + 64, fc_w, nullptr, scalar, fc_b, done, out);
}